// Round 8
// baseline (247.385 us; speedup 1.0000x reference)
//
#include <hip/hip_runtime.h>
#include <math.h>

// Problem constants: N=500000, NFEAT=64, K=8, HK=64
constexpr int NS    = 500000;
constexpr int NF    = 64;
constexpr int KG    = 8;
constexpr int HKC   = 64;
constexpr int NCELL = KG * HKC;            // 512 histogram cells
constexpr int RPW   = 32;                  // rows per wave (NS % 32 == 0)
constexpr int TPB   = 1024;                // 16 waves per block
constexpr int NBLK  = 256;                 // 1 block per CU (132 KB LDS)
constexpr int NTILE = NS / RPW;            // 15625 row-tiles (exact)
constexpr int NWAVES = NBLK * (TPB / 64);  // 4096 waves, grid-stride over tiles

typedef __attribute__((ext_vector_type(8))) _Float16 half8;
typedef __attribute__((ext_vector_type(4))) float f32x4;

// Kernel 1: w = exp(z) split to fp16 hi/lo; zero A.
__global__ void prep_kernel(const float* __restrict__ z,
                            _Float16* __restrict__ w_hi,
                            _Float16* __restrict__ w_lo,
                            float* __restrict__ A) {
    int i = blockIdx.x * blockDim.x + threadIdx.x;
    if (i < KG * HKC * NF) {
        float w = expf(z[i]);
        _Float16 h = (_Float16)w;           // RNE
        w_hi[i] = h;
        w_lo[i] = (_Float16)(w - (float)h); // residual: ~2^-22 total pair error
    }
    if (i < NCELL) A[i] = 0.0f;
}

// Main kernel R14 (resubmitted after infra failure): R9 skeleton
// (persistent-W, RPW=32, TPB=1024, 16 waves/CU — empirically best: 101.6)
// + epilogue pipeline.
// R13 ranking: occupancy (16 waves) beats LDS-traffic halving (8 waves).
// R9's residual: per-g serial tail ~350 cyc (fmax tree + 16-deep scan +
// TWO sequential LDS round-trips) -> per-wave matrix duty ~40%.
// R14: (1) 3-way parallel cross-lane combine (6 ds_bpermute, ONE round
// trip; identical result by associativity of lexicographic best-of-4);
// (2) pulls for group g issued at end of g, wait+combine deferred until
// AFTER g+1's MFMA block — the compiler's own W-read lgkmcnt waits drain
// the in-order DS queue, so the round-trip hides under matrix work;
// (3) R10's split h-scan (4 indep depth-4 chains; harness-verified form).
// All decisions bit-identical to R9. Carried state ~16 regs: ~112 < 128.
// LDS: 131072 + 2048 + 2048 = 135168 B < 163840 B gfx950 per-WG limit.
__global__ __launch_bounds__(TPB, 4) void monn_mfma_kernel(
    const float* __restrict__ x,
    const _Float16* __restrict__ w_hi,
    const _Float16* __restrict__ w_lo,
    const float* __restrict__ t,
    float* __restrict__ y,
    float* __restrict__ A) {

    __shared__ __align__(16) char smem[2 * KG * 8192];   // hi @0, lo @65536
    __shared__ __align__(16) float t_lds[KG * HKC];      // 2 KB
    __shared__ unsigned lhist[NCELL];

    const int tid = threadIdx.x;

    // --- one-time staging: 128 KB of w (coalesced, XOR-swizzled), t, hist ---
    {
        const float4* sh = reinterpret_cast<const float4*>(w_hi);
        const float4* sl = reinterpret_cast<const float4*>(w_lo);
#pragma unroll
        for (int i = 0; i < 4; ++i) {
            const int ci  = i * 1024 + tid;         // 16B chunk id, 0..4095
            const int row = (ci >> 3) & 63;         // w-col within group
            const int ch  = ci & 7;                 // 16B chunk within row
            const int addr = (ci >> 9) * 8192 + row * 128 + ((ch ^ (row & 7)) << 4);
            *reinterpret_cast<float4*>(smem + addr)         = sh[ci];
            *reinterpret_cast<float4*>(smem + 65536 + addr) = sl[ci];
        }
        if (tid < 128)
            reinterpret_cast<float4*>(t_lds)[tid] =
                reinterpret_cast<const float4*>(t)[tid];
        if (tid < NCELL) lhist[tid] = 0u;
    }
    __syncthreads();   // the ONLY barrier before the final flush

    const int lane = tid & 63;
    const int m  = lane & 15;
    const int q  = lane >> 4;
    const int q4 = q * 4;
    // ds_bpermute byte-addrs for the 3-way cross-q exchange (lanes ^16/^32/^48)
    const int a16 = ((lane ^ 16) << 2);
    const int a32 = ((lane ^ 32) << 2);
    const int a48 = ((lane ^ 48) << 2);
    const int x7  = m & 7;
    const int rb0 = m * 128 + (((0 + q) ^ x7) << 4);
    const int rb1 = m * 128 + (((4 + q) ^ x7) << 4);
    const int gwave = blockIdx.x * (TPB / 64) + (tid >> 6);

#pragma unroll 1
    for (int tile = gwave; tile < NTILE; tile += NWAVES) {
        const long base = (long)tile * RPW;

        // --- Load 32 x rows, split to fp16 hi/lo (B-operand layout) ---
        half8 Xh[2][2], Xl[2][2];
#pragma unroll
        for (int rt = 0; rt < 2; ++rt) {
            const float* xp = x + (base + rt * 16 + m) * NF;
#pragma unroll
            for (int s = 0; s < 2; ++s) {
                const int k0 = s * 32 + q * 8;
                const float4 v0 = *reinterpret_cast<const float4*>(xp + k0);
                const float4 v1 = *reinterpret_cast<const float4*>(xp + k0 + 4);
                const float f[8] = {v0.x, v0.y, v0.z, v0.w, v1.x, v1.y, v1.z, v1.w};
#pragma unroll
                for (int j = 0; j < 8; ++j) {
                    _Float16 h = (_Float16)f[j];
                    Xh[rt][s][j] = h;
                    Xl[rt][s][j] = (_Float16)(f[j] - (float)h);
                }
            }
        }

        float ymin[2] = {INFINITY, INFINITY};
        int   code[2] = {0, 0};
        // pending epilogue state for group g-1 (carried across iterations)
        float pv[2];            int ph[2];
        float qv[2][3];         int qh[2][3];   // pulled candidates (^16,^32,^48)

#pragma unroll 1
        for (int g = 0; g < KG; ++g) {
            // --- acc init: bias folded; lane's w-cols are c*16 + q4 + j ---
            f32x4 acc[4][2];   // [c (w tile)][rt (x tile)]
#pragma unroll
            for (int c = 0; c < 4; ++c) {
                const float4 tv = *reinterpret_cast<const float4*>(
                    t_lds + g * HKC + c * 16 + q4);
                acc[c][0] = (f32x4){tv.x, tv.y, tv.z, tv.w};
                acc[c][1] = acc[c][0];
            }

            // --- MFMA block (R9 form: load 8 W frags, 3 independent passes;
            //     per-acc order hh, lh, hl; s0 then s1 -> bit-identical) ---
#pragma unroll
            for (int s = 0; s < 2; ++s) {
                const int rb = (s ? rb1 : rb0) + g * 8192;
                half8 Wh[4], Wl[4];
#pragma unroll
                for (int c = 0; c < 4; ++c) {   // ds_read_b128, imm offsets
                    Wh[c] = *reinterpret_cast<const half8*>(smem + rb + c * 2048);
                    Wl[c] = *reinterpret_cast<const half8*>(smem + 65536 + rb + c * 2048);
                }
#pragma unroll
                for (int c = 0; c < 4; ++c)
#pragma unroll
                    for (int rt = 0; rt < 2; ++rt)
                        acc[c][rt] = __builtin_amdgcn_mfma_f32_16x16x32_f16(Wh[c], Xh[rt][s], acc[c][rt], 0, 0, 0);
#pragma unroll
                for (int c = 0; c < 4; ++c)
#pragma unroll
                    for (int rt = 0; rt < 2; ++rt)
                        acc[c][rt] = __builtin_amdgcn_mfma_f32_16x16x32_f16(Wl[c], Xh[rt][s], acc[c][rt], 0, 0, 0);
#pragma unroll
                for (int c = 0; c < 4; ++c)
#pragma unroll
                    for (int rt = 0; rt < 2; ++rt)
                        acc[c][rt] = __builtin_amdgcn_mfma_f32_16x16x32_f16(Wh[c], Xl[rt][s], acc[c][rt], 0, 0, 0);
            }

            // --- finish epilogue of g-1: pulls were issued last iteration
            //     and are already drained by this block's W-read lgkmcnt
            //     waits (in-order DS returns). VALU-only; also fills the
            //     MFMA->VALU hazard window before the acc reads below. ---
            if (g > 0) {
#pragma unroll
                for (int rt = 0; rt < 2; ++rt) {
                    float v = pv[rt]; int h = ph[rt];
#pragma unroll
                    for (int e = 0; e < 3; ++e) {
                        const bool take = (qv[rt][e] > v) ||
                                          (qv[rt][e] == v && qh[rt][e] < h);
                        v = take ? qv[rt][e] : v;
                        h = take ? qh[rt][e] : h;
                    }
                    // running min over groups: strict < keeps first (lowest g)
                    const bool better = v < ymin[rt];
                    ymin[rt] = fminf(ymin[rt], v);
                    code[rt] = better ? (((g - 1) << 6) | h) : code[rt];
                }
            }

            // --- start epilogue of g: fmax tree + split scan + issue pulls ---
#pragma unroll
            for (int rt = 0; rt < 2; ++rt) {
                const float t01 = fmaxf(acc[0][rt][0], acc[0][rt][1]);
                const float t23 = fmaxf(acc[0][rt][2], acc[0][rt][3]);
                const float t45 = fmaxf(acc[1][rt][0], acc[1][rt][1]);
                const float t67 = fmaxf(acc[1][rt][2], acc[1][rt][3]);
                const float t89 = fmaxf(acc[2][rt][0], acc[2][rt][1]);
                const float tab = fmaxf(acc[2][rt][2], acc[2][rt][3]);
                const float tcd = fmaxf(acc[3][rt][0], acc[3][rt][1]);
                const float tef = fmaxf(acc[3][rt][2], acc[3][rt][3]);
                const float m0 = fmaxf(t01, t23);
                const float m1 = fmaxf(t45, t67);
                const float m2 = fmaxf(t89, tab);
                const float m3 = fmaxf(tcd, tef);
                const float v = fmaxf(fmaxf(m0, m1), fmaxf(m2, m3));
                // argmax, first-occurrence (smallest c, then smallest j):
                // 4 independent within-c scans + descending-c select
                // (R10 form, harness-verified; identical to 16-deep scan)
                int j0 = 0, j1 = 0, j2 = 0, j3 = 0;
#pragma unroll
                for (int j = 3; j >= 0; --j) {
                    j0 = (acc[0][rt][j] == v) ? j : j0;
                    j1 = (acc[1][rt][j] == v) ? j : j1;
                    j2 = (acc[2][rt][j] == v) ? j : j2;
                    j3 = (acc[3][rt][j] == v) ? j : j3;
                }
                int h = 48 | j3;               // at least one mc == v holds
                h = (m2 == v) ? (32 | j2) : h;
                h = (m1 == v) ? (16 | j1) : h;
                h = (m0 == v) ? (0  | j0) : h;
                h |= q4;
                pv[rt] = v;  ph[rt] = h;
                // 6 parallel pulls, one round trip, waited next iteration.
                // Lexicographic best-of-4 is associative/commutative ->
                // identical to R9's two-step pairwise combine.
                const int vi = __float_as_int(v);
                qv[rt][0] = __int_as_float(__builtin_amdgcn_ds_bpermute(a16, vi));
                qv[rt][1] = __int_as_float(__builtin_amdgcn_ds_bpermute(a32, vi));
                qv[rt][2] = __int_as_float(__builtin_amdgcn_ds_bpermute(a48, vi));
                qh[rt][0] = __builtin_amdgcn_ds_bpermute(a16, h);
                qh[rt][1] = __builtin_amdgcn_ds_bpermute(a32, h);
                qh[rt][2] = __builtin_amdgcn_ds_bpermute(a48, h);
            }
        }

        // --- drain pipeline: finish epilogue of g = KG-1 ---
#pragma unroll
        for (int rt = 0; rt < 2; ++rt) {
            float v = pv[rt]; int h = ph[rt];
#pragma unroll
            for (int e = 0; e < 3; ++e) {
                const bool take = (qv[rt][e] > v) ||
                                  (qv[rt][e] == v && qh[rt][e] < h);
                v = take ? qv[rt][e] : v;
                h = take ? qh[rt][e] : h;
            }
            const bool better = v < ymin[rt];
            ymin[rt] = fminf(ymin[rt], v);
            code[rt] = better ? (((KG - 1) << 6) | h) : code[rt];
        }

        // q==0 lanes write y and bump the block histogram (LDS, banked)
        if (q == 0) {
#pragma unroll
            for (int rt = 0; rt < 2; ++rt) {
                y[base + rt * 16 + m] = ymin[rt];
                atomicAdd(&lhist[code[rt]], 1u);
            }
        }
    }

    __syncthreads();
    // zero-skip flush straight into A: 256 blocks x <=512 cells ->
    // <=256 conflicting atomics per address, negligible
    for (int i = tid; i < NCELL; i += TPB) {
        const unsigned c = lhist[i];
        if (c) atomicAdd(&A[i], (float)c);
    }
}

extern "C" void kernel_launch(void* const* d_in, const int* in_sizes, int n_in,
                              void* d_out, int out_size, void* d_ws, size_t ws_size,
                              hipStream_t stream) {
    const float* x = (const float*)d_in[0];  // [NS, NF]
    const float* z = (const float*)d_in[1];  // [KG, HKC, NF]
    const float* t = (const float*)d_in[2];  // [KG, HKC]

    float* y = (float*)d_out;        // [NS]
    float* A = (float*)d_out + NS;   // [NCELL]

    _Float16* w_hi = (_Float16*)d_ws;                          // 64 KB
    _Float16* w_lo = w_hi + (size_t)KG * HKC * NF;             // 64 KB

    prep_kernel<<<128, 256, 0, stream>>>(z, w_hi, w_lo, A);
    monn_mfma_kernel<<<NBLK, TPB, 0, stream>>>(x, w_hi, w_lo, t, y, A);
}

// Round 9
// 234.408 us; speedup vs baseline: 1.0554x; 1.0554x over previous
//
#include <hip/hip_runtime.h>
#include <math.h>

// Problem constants: N=500000, NFEAT=64, K=8, HK=64
constexpr int NS    = 500000;
constexpr int NF    = 64;
constexpr int KG    = 8;
constexpr int HKC   = 64;
constexpr int NCELL = KG * HKC;            // 512 histogram cells
constexpr int RPW   = 32;                  // rows per wave (NS % 32 == 0)
constexpr int TPB   = 1024;                // 16 waves per block
constexpr int NBLK  = 256;                 // 1 block per CU (132 KB LDS)
constexpr int NTILE = NS / RPW;            // 15625 row-tiles (exact, no tail)
constexpr int NWAVES = NBLK * (TPB / 64);  // 4096 waves, grid-stride over tiles

typedef __attribute__((ext_vector_type(8)))  _Float16 half8;
typedef __attribute__((ext_vector_type(16))) float    f32x16;

// Kernel 1: w = exp(z) split to fp16 hi/lo; zero A.
__global__ void prep_kernel(const float* __restrict__ z,
                            _Float16* __restrict__ w_hi,
                            _Float16* __restrict__ w_lo,
                            float* __restrict__ A) {
    int i = blockIdx.x * blockDim.x + threadIdx.x;
    if (i < KG * HKC * NF) {
        float w = expf(z[i]);
        _Float16 h = (_Float16)w;           // RNE
        w_hi[i] = h;
        w_lo[i] = (_Float16)(w - (float)h); // residual: ~2^-22 total pair error
    }
    if (i < NCELL) A[i] = 0.0f;
}

// Main kernel R15: persistent-W + mfma_f32_32x32x16_f16.
// R14 post-mortem: R9's MfmaUtil 43% + VALUBusy 48% are SEPARATE pipes
// (m114) -> 91% issue-busy; rescheduling can't win (R10/R11/R13/R14 all
// regressed). R15 REDUCES ISSUED WORK: same FLOPs in 192 MFMA/tile (was
// 384) at the better 32x32 rate (matrix floor 47->39 us), ONE epilogue
// per group (N=32 covers all rows; scan VALU -40%), ONE cross-lane
// exchange (lane^32) instead of two stages (DS 64->16/tile).
// LDS W layout is fragment-linear (chunk-major [g][c][ks][lane][16B]):
// every ds_read_b128 is base=lane*16 + immediate -> conflict-free, no
// swizzle. Fragment maps: C row=(r&3)+8(r>>2)+4(lane>>5), col=lane&31
// (m74/m101); A/B k = 8*(lane>>5)+i (k-blocked, same pattern the working
// 16x16 kernel validates with lane>>4).
// Accumulation k-chunk order changes (16 vs 32) -> not bit-identical to
// R9; method error unchanged (~2^-22 pair split).
// LDS: 131072 + 2048 + 2048 = 135168 B < 163840 B gfx950 per-WG limit.
// Regs: X 32 + acc 32 + W 16 + temps ~110 < 128 cap of (1024,4).
__global__ __launch_bounds__(TPB, 4) void monn_mfma_kernel(
    const float* __restrict__ x,
    const _Float16* __restrict__ w_hi,
    const _Float16* __restrict__ w_lo,
    const float* __restrict__ t,
    float* __restrict__ y,
    float* __restrict__ A) {

    __shared__ __align__(16) char smem[2 * KG * 8192];   // hi @0, lo @65536
    __shared__ __align__(16) float t_lds[KG * HKC];      // 2 KB
    __shared__ unsigned lhist[NCELL];

    const int tid = threadIdx.x;

    // --- one-time staging: fragment-linear. Chunk ci (16B) holds, for
    //     lane-slot l = ci&63, ks = (ci>>6)&3, c = (ci>>8)&1, g = ci>>9:
    //     W[g][c*32 + (l&31)][ks*16 + (l>>5)*8 + 0..7]  (A-operand frag).
    //     LDS byte addr of chunk = ci*16 (linear). ---
    {
        const float4* sh = reinterpret_cast<const float4*>(w_hi);
        const float4* sl = reinterpret_cast<const float4*>(w_lo);
#pragma unroll
        for (int i = 0; i < 4; ++i) {
            const int ci = i * 1024 + tid;          // 0..4095
            const int l  = ci & 63;
            const int ks = (ci >> 6) & 3;
            const int c  = (ci >> 8) & 1;
            const int g  = ci >> 9;
            const int gi = (g * 64 + c * 32 + (l & 31)) * 8 + ks * 2 + (l >> 5);
            *reinterpret_cast<float4*>(smem + ci * 16)         = sh[gi];
            *reinterpret_cast<float4*>(smem + 65536 + ci * 16) = sl[gi];
        }
        if (tid < 128)
            reinterpret_cast<float4*>(t_lds)[tid] =
                reinterpret_cast<const float4*>(t)[tid];
        if (tid < NCELL) lhist[tid] = 0u;
    }
    __syncthreads();   // the ONLY barrier before the final flush

    const int lane = tid & 63;
    const int col  = lane & 31;        // x-row within tile (MFMA N index)
    const int hig  = lane >> 5;        // k-subgroup within 16-block
    const int hi4  = hig * 4;          // C-row offset for this half-wave
    const int a32  = ((lane ^ 32) << 2);  // bpermute addr: other hi half
    const int wb   = lane * 16;        // W fragment LDS base (linear)
    const int gwave = blockIdx.x * (TPB / 64) + (tid >> 6);

#pragma unroll 1
    for (int tile = gwave; tile < NTILE; tile += NWAVES) {
        const long base = (long)tile * RPW;

        // --- Load 32 x rows, split to fp16 hi/lo (B-operand layout:
        //     col = lane&31, k = ks*16 + hig*8 + i) ---
        half8 Xh[4], Xl[4];
        {
            const float* xp = x + (base + col) * NF + hig * 8;
#pragma unroll
            for (int ks = 0; ks < 4; ++ks) {
                const float4 v0 = *reinterpret_cast<const float4*>(xp + ks * 16);
                const float4 v1 = *reinterpret_cast<const float4*>(xp + ks * 16 + 4);
                const float f[8] = {v0.x, v0.y, v0.z, v0.w, v1.x, v1.y, v1.z, v1.w};
#pragma unroll
                for (int j = 0; j < 8; ++j) {
                    _Float16 h = (_Float16)f[j];
                    Xh[ks][j] = h;
                    Xl[ks][j] = (_Float16)(f[j] - (float)h);
                }
            }
        }

        float ymin = INFINITY;
        int   code = 0;

#pragma unroll 1
        for (int g = 0; g < KG; ++g) {
            // --- acc init: bias folded. acc[c][r] covers w-col
            //     c*32 + (r&3) + 8*(r>>2) + hi4, x-row = col. ---
            f32x16 acc[2];
#pragma unroll
            for (int c = 0; c < 2; ++c)
#pragma unroll
                for (int Q = 0; Q < 4; ++Q) {
                    const float4 tv = *reinterpret_cast<const float4*>(
                        t_lds + g * HKC + c * 32 + 8 * Q + hi4);
                    acc[c][4 * Q + 0] = tv.x;
                    acc[c][4 * Q + 1] = tv.y;
                    acc[c][4 * Q + 2] = tv.z;
                    acc[c][4 * Q + 3] = tv.w;
                }

            // --- MFMA: per k-block ks, per-acc order hh, lh, hl ---
#pragma unroll
            for (int ks = 0; ks < 4; ++ks) {
                const int ob = g * 8192 + ks * 1024 + wb;
                const half8 Wh0 = *reinterpret_cast<const half8*>(smem + ob);
                const half8 Wh1 = *reinterpret_cast<const half8*>(smem + ob + 4096);
                const half8 Wl0 = *reinterpret_cast<const half8*>(smem + 65536 + ob);
                const half8 Wl1 = *reinterpret_cast<const half8*>(smem + 65536 + ob + 4096);
                acc[0] = __builtin_amdgcn_mfma_f32_32x32x16_f16(Wh0, Xh[ks], acc[0], 0, 0, 0);
                acc[1] = __builtin_amdgcn_mfma_f32_32x32x16_f16(Wh1, Xh[ks], acc[1], 0, 0, 0);
                acc[0] = __builtin_amdgcn_mfma_f32_32x32x16_f16(Wl0, Xh[ks], acc[0], 0, 0, 0);
                acc[1] = __builtin_amdgcn_mfma_f32_32x32x16_f16(Wl1, Xh[ks], acc[1], 0, 0, 0);
                acc[0] = __builtin_amdgcn_mfma_f32_32x32x16_f16(Wh0, Xl[ks], acc[0], 0, 0, 0);
                acc[1] = __builtin_amdgcn_mfma_f32_32x32x16_f16(Wh1, Xl[ks], acc[1], 0, 0, 0);
            }

            // --- epilogue (ONE per group: lane holds 32 w-cols of x-row
            //     `col`; other 32 w-cols live in lane^32) ---
            float qm[2][4];
#pragma unroll
            for (int c = 0; c < 2; ++c)
#pragma unroll
                for (int Q = 0; Q < 4; ++Q)
                    qm[c][Q] = fmaxf(fmaxf(acc[c][4 * Q], acc[c][4 * Q + 1]),
                                     fmaxf(acc[c][4 * Q + 2], acc[c][4 * Q + 3]));
            float v = fmaxf(fmaxf(fmaxf(qm[0][0], qm[0][1]), fmaxf(qm[0][2], qm[0][3])),
                            fmaxf(fmaxf(qm[1][0], qm[1][1]), fmaxf(qm[1][2], qm[1][3])));
            // first-occurrence argmax (smallest w-col): 8 independent
            // within-quartet scans + descending-(c,Q) select chain
            int jq[2][4] = {{0, 0, 0, 0}, {0, 0, 0, 0}};
#pragma unroll
            for (int c = 0; c < 2; ++c)
#pragma unroll
                for (int Q = 0; Q < 4; ++Q)
#pragma unroll
                    for (int j = 3; j >= 0; --j)
                        jq[c][Q] = (acc[c][4 * Q + j] == v) ? j : jq[c][Q];
            int h = 0;
#pragma unroll
            for (int c = 1; c >= 0; --c)
#pragma unroll
                for (int Q = 3; Q >= 0; --Q)
                    h = (qm[c][Q] == v) ? (c * 32 + 8 * Q + jq[c][Q]) : h;
            h |= hi4;   // bit 2 free: jq in bits 0-1, 8Q bits 3-4, c bit 5
            // cross-half combine: lexicographic (max v, tie -> smaller h)
            {
                const float v2 = __int_as_float(
                    __builtin_amdgcn_ds_bpermute(a32, __float_as_int(v)));
                const int h2 = __builtin_amdgcn_ds_bpermute(a32, h);
                const bool take = (v2 > v) || (v2 == v && h2 < h);
                v = take ? v2 : v;  h = take ? h2 : h;
            }
            // running min over groups: strict < keeps first (lowest g)
            const bool better = v < ymin;
            ymin = fminf(ymin, v);
            code = better ? ((g << 6) | h) : code;
        }

        // lanes 0..31 own distinct x-rows; write y and bump histogram
        if (lane < 32) {
            y[base + col] = ymin;
            atomicAdd(&lhist[code], 1u);
        }
    }

    __syncthreads();
    // zero-skip flush straight into A: 256 blocks x <=512 cells ->
    // <=256 conflicting atomics per address, negligible
    for (int i = tid; i < NCELL; i += TPB) {
        const unsigned c = lhist[i];
        if (c) atomicAdd(&A[i], (float)c);
    }
}

extern "C" void kernel_launch(void* const* d_in, const int* in_sizes, int n_in,
                              void* d_out, int out_size, void* d_ws, size_t ws_size,
                              hipStream_t stream) {
    const float* x = (const float*)d_in[0];  // [NS, NF]
    const float* z = (const float*)d_in[1];  // [KG, HKC, NF]
    const float* t = (const float*)d_in[2];  // [KG, HKC]

    float* y = (float*)d_out;        // [NS]
    float* A = (float*)d_out + NS;   // [NCELL]

    _Float16* w_hi = (_Float16*)d_ws;                          // 64 KB
    _Float16* w_lo = w_hi + (size_t)KG * HKC * NF;             // 64 KB

    prep_kernel<<<128, 256, 0, stream>>>(z, w_hi, w_lo, A);
    monn_mfma_kernel<<<NBLK, TPB, 0, stream>>>(x, w_hi, w_lo, t, y, A);
}